// Round 9
// baseline (588.487 us; speedup 1.0000x reference)
//
#include <hip/hip_runtime.h>
#include <math.h>

using f32x4 = __attribute__((ext_vector_type(4))) float;
typedef __attribute__((ext_vector_type(4))) int i32x4;
typedef __attribute__((ext_vector_type(8))) int i32x8;
typedef unsigned char u8;

#define BS    8192
#define CDIM  512
#define MROWS 32768
#define NC    16                // n-chunks (grid.x) -> 1024 blocks = 4/CU
#define CHUNK (MROWS / NC)      // 2048
#define TN    16                // B rows per step (register tile, no LDS)
#define TQ    128               // queries per block (32 per wave)
#define KTOP  5
#define STEPS (CHUNK / TN)      // 128
#define ROWB  512               // fp8 row bytes
#define KEY_INIT 0x3FFF8000u    // enc_key(-2.0f, 0)
#define SCL   0x7F7F7F7F        // E8M0 scale = 1.0 in all 4 bytes

// ---------- key packing: monotonic fp32 order bits [31:15] | index [14:0] ----
__device__ __forceinline__ unsigned enc_key(float s, int n) {
    unsigned u = __float_as_uint(s);
    u ^= (unsigned)((int)u >> 31) | 0x80000000u;   // monotonic map
    return (u & 0xFFFF8000u) | (unsigned)n;
}
__device__ __forceinline__ float dec_score(unsigned k) {
    unsigned u = k & 0xFFFF8000u;
    u = (u & 0x80000000u) ? (u ^ 0x80000000u) : ~u;
    return __uint_as_float(u);
}

// sorted-descending top-5 list of packed keys, branchless bubble insert
__device__ __forceinline__ void ins_nb(unsigned (&ks)[KTOP], unsigned k) {
    unsigned t = k;
#pragma unroll
    for (int j = 0; j < KTOP; ++j) {
        unsigned hi = t > ks[j] ? t : ks[j];
        unsigned lo = t > ks[j] ? ks[j] : t;
        ks[j] = hi; t = lo;
    }
}

// max across a 16-lane DPP row (VALU-only)
__device__ __forceinline__ float dpp_fmax16(float x) {
    int t;
    t = __builtin_amdgcn_update_dpp(0, __float_as_int(x), 0xB1, 0xF, 0xF, true);  // xor 1
    x = fmaxf(x, __int_as_float(t));
    t = __builtin_amdgcn_update_dpp(0, __float_as_int(x), 0x4E, 0xF, 0xF, true);  // xor 2
    x = fmaxf(x, __int_as_float(t));
    t = __builtin_amdgcn_update_dpp(0, __float_as_int(x), 0x141, 0xF, 0xF, true); // xor 4
    x = fmaxf(x, __int_as_float(t));
    t = __builtin_amdgcn_update_dpp(0, __float_as_int(x), 0x140, 0xF, 0xF, true); // xor 8
    x = fmaxf(x, __int_as_float(t));
    return x;
}

// ---------- kernel 1: row L2-normalize fp32 -> fp8 e4m3 (both inputs) -------
__global__ void nrm_cast2(const float* __restrict__ memM, u8* __restrict__ mn,
                          const float* __restrict__ x, u8* __restrict__ qn) {
    int wave = threadIdx.x >> 6, lane = threadIdx.x & 63;
    int row = blockIdx.x * 4 + wave;
    const float* in;
    u8* out;
    if (row < MROWS) { in = memM + (size_t)row * CDIM; out = mn + (size_t)row * ROWB; }
    else             { int r = row - MROWS; in = x + (size_t)r * CDIM; out = qn + (size_t)r * ROWB; }
    const float* rp = in + lane * 8;
    float4 v0 = *(const float4*)rp;
    float4 v1 = *(const float4*)(rp + 4);
    float ss = v0.x * v0.x + v0.y * v0.y + v0.z * v0.z + v0.w * v0.w
             + v1.x * v1.x + v1.y * v1.y + v1.z * v1.z + v1.w * v1.w;
#pragma unroll
    for (int d = 1; d < 64; d <<= 1) ss += __shfl_xor(ss, d);
    float sc = 1.0f / fmaxf(sqrtf(ss), 1e-12f);
    int lo = __builtin_amdgcn_cvt_pk_fp8_f32(v0.x * sc, v0.y * sc, 0, false);
    lo     = __builtin_amdgcn_cvt_pk_fp8_f32(v0.z * sc, v0.w * sc, lo, true);
    int hi = __builtin_amdgcn_cvt_pk_fp8_f32(v1.x * sc, v1.y * sc, 0, false);
    hi     = __builtin_amdgcn_cvt_pk_fp8_f32(v1.z * sc, v1.w * sc, hi, true);
    uint2 o; o.x = (unsigned)lo; o.y = (unsigned)hi;
    *(uint2*)(out + lane * 8) = o;
}

// ---------- B-row register load: 8 x dwordx4 -> 4 x i32x8 -------------------
__device__ __forceinline__ void load_b(i32x8 (&b)[4], const u8* p) {
#pragma unroll
    for (int t = 0; t < 4; ++t) {
        i32x4 lo = *(const i32x4*)(p + t * 128);
        i32x4 hi = *(const i32x4*)(p + t * 128 + 16);
        b[t] = __builtin_shufflevector(lo, hi, 0, 1, 2, 3, 4, 5, 6, 7);
    }
}

// ---------- kernel 2: no-LDS MX-fp8 MFMA sim + per-chunk top-5 --------------
// grid = (NC, BS/TQ) = (16,64) = 1024 blocks -> 4 blocks/CU (no LDS cap,
// VGPR ~100). Round-8 result: no-LDS is latency-bound (MfmaUtil 11.5%,
// 60% idle) because loop-carried b[] reuse forces a vmcnt drain before each
// step's MFMAs and 2 waves/SIMD can't cover ~200cy L2 latency. Fix here:
// (1) explicit unroll-2 ping-pong bA/bB -- step it+1's 8 loads issue before
// step it's MFMAs+filter (~1 step of issue covers L2 latency); (2) 4
// blocks/CU of TLP. Filter stays one step behind MFMAs (round-6 win).
__global__ __launch_bounds__(256, 2) void simtopk(
        const u8* __restrict__ qn, const u8* __restrict__ mn,
        unsigned* __restrict__ cand) {
    const int tid  = threadIdx.x;
    const int wave = tid >> 6, lane = tid & 63;
    const int quad = lane >> 4, c16 = lane & 15;
    const int nc = blockIdx.x;
    const int qt = blockIdx.y;
    const int qw = qt * TQ + wave * 32;
    const int nb0 = nc * CHUNK;

    // persistent A fragments: 2 q-subtiles x 4 k128-chunks x 32B = 64 VGPRs
    i32x8 a[2][4];
#pragma unroll
    for (int s = 0; s < 2; ++s) {
        const u8* p = qn + (size_t)(qw + s * 16 + c16) * ROWB + quad * 32;
#pragma unroll
        for (int t = 0; t < 4; ++t) {
            i32x4 lo = *(const i32x4*)(p + t * 128);
            i32x4 hi = *(const i32x4*)(p + t * 128 + 16);
            a[s][t] = __builtin_shufflevector(lo, hi, 0, 1, 2, 3, 4, 5, 6, 7);
        }
    }

    unsigned keys[8][KTOP];
    float thr[8];
#pragma unroll
    for (int l = 0; l < 8; ++l) {
        thr[l] = -2.0f;
#pragma unroll
        for (int j = 0; j < KTOP; ++j) keys[l][j] = KEY_INIT;
    }

    // B pointer: this lane's row within the 16-row window, 32B sub-chunk
    const u8* pB = mn + (size_t)(nb0 + c16) * ROWB + quad * 32;

    // carried (previous-step) accumulators + their row index
    f32x4 p0 = {-2.f, -2.f, -2.f, -2.f}, p1 = p0;
    int np = nb0;

    i32x8 bA[4], bB[4];
    load_b(bA, pB);                      // step 0

    for (int it = 0; it < STEPS; it += 2) {
        // ---- prefetch step it+1 (always exists: STEPS even) ----
        load_b(bB, pB + TN * ROWB);

        // ---- MFMA step it with bA ----
        f32x4 acc0 = {0.f, 0.f, 0.f, 0.f}, acc1 = {0.f, 0.f, 0.f, 0.f};
#pragma unroll
        for (int t = 0; t < 4; ++t) {
            acc0 = __builtin_amdgcn_mfma_scale_f32_16x16x128_f8f6f4(
                       a[0][t], bA[t], acc0, 0, 0, 0, SCL, 0, SCL);
            acc1 = __builtin_amdgcn_mfma_scale_f32_16x16x128_f8f6f4(
                       a[1][t], bA[t], acc1, 0, 0, 0, SCL, 0, SCL);
        }
        // filter previous step's accs (independent of in-flight loads/MFMAs)
#pragma unroll
        for (int j = 0; j < 4; ++j) {
            if (p0[j] > thr[j])     ins_nb(keys[j],     enc_key(p0[j], np));
            if (p1[j] > thr[4 + j]) ins_nb(keys[4 + j], enc_key(p1[j], np));
        }
        p0 = acc0; p1 = acc1;
        np = nb0 + it * TN + c16;

        // ---- prefetch step it+2 ----
        if (it + 2 < STEPS) load_b(bA, pB + 2 * TN * ROWB);

        // ---- MFMA step it+1 with bB ----
        f32x4 acc2 = {0.f, 0.f, 0.f, 0.f}, acc3 = {0.f, 0.f, 0.f, 0.f};
#pragma unroll
        for (int t = 0; t < 4; ++t) {
            acc2 = __builtin_amdgcn_mfma_scale_f32_16x16x128_f8f6f4(
                       a[0][t], bB[t], acc2, 0, 0, 0, SCL, 0, SCL);
            acc3 = __builtin_amdgcn_mfma_scale_f32_16x16x128_f8f6f4(
                       a[1][t], bB[t], acc3, 0, 0, 0, SCL, 0, SCL);
        }
        // filter step it's accs
#pragma unroll
        for (int j = 0; j < 4; ++j) {
            if (p0[j] > thr[j])     ins_nb(keys[j],     enc_key(p0[j], np));
            if (p1[j] > thr[4 + j]) ins_nb(keys[4 + j], enc_key(p1[j], np));
        }
        if (((it + 1) & 7) == 7) {   // every 8 steps == every 128 rows
#pragma unroll
            for (int l = 0; l < 8; ++l)
                thr[l] = dpp_fmax16(fmaxf(thr[l], dec_score(keys[l][KTOP - 1])));
        }
        p0 = acc2; p1 = acc3;
        np = nb0 + (it + 1) * TN + c16;

        pB += 2 * TN * ROWB;
    }

    // drain the final step's accumulators
#pragma unroll
    for (int j = 0; j < 4; ++j) {
        if (p0[j] > thr[j])     ins_nb(keys[j],     enc_key(p0[j], np));
        if (p1[j] > thr[4 + j]) ins_nb(keys[4 + j], enc_key(p1[j], np));
    }

    // merge the 16 column-lanes of each quad (disjoint n subsets -> union top5)
#pragma unroll
    for (int d = 1; d <= 8; d <<= 1) {
#pragma unroll
        for (int l = 0; l < 8; ++l) {
            unsigned rk[KTOP];
#pragma unroll
            for (int j = 0; j < KTOP; ++j) rk[j] = (unsigned)__shfl_xor((int)keys[l][j], d);
#pragma unroll
            for (int j = 0; j < KTOP; ++j) ins_nb(keys[l], rk[j]);
        }
    }

    // writer lane c16==l emits list l for query qw + (l>>2)*16 + quad*4 + (l&3)
#pragma unroll
    for (int l = 0; l < 8; ++l) {
        if (c16 == l) {
            const int q = qw + (l >> 2) * 16 + quad * 4 + (l & 3);
            unsigned* cp = cand + ((size_t)q * NC + nc) * KTOP;
#pragma unroll
            for (int j = 0; j < KTOP; ++j) cp[j] = keys[l][j];
        }
    }
}

// ---------- kernel 3: global top-5 merge + softmax + gather + residual ------
// NC*KTOP = 80 candidates per query: each lane holds up to 2 keys.
__global__ void epilogue(const float* __restrict__ x, const float* __restrict__ mem,
                         const unsigned* __restrict__ cand, float* __restrict__ out) {
    int wave = threadIdx.x >> 6, lane = threadIdx.x & 63;
    int q = blockIdx.x * 4 + wave;

    const unsigned* cp0 = cand + (size_t)q * (NC * KTOP);
    unsigned k0 = cp0[lane];                                   // 64 of 80
    unsigned k1 = (lane < NC * KTOP - 64) ? cp0[64 + lane] : 0u;
    float s[KTOP]; int id[KTOP];
#pragma unroll
    for (int k = 0; k < KTOP; ++k) {
        unsigned m = k0 > k1 ? k0 : k1;
#pragma unroll
        for (int d = 32; d; d >>= 1) {
            unsigned o = (unsigned)__shfl_xor((int)m, d);
            m = o > m ? o : m;
        }
        s[k] = dec_score(m);
        id[k] = (int)(m & 0x7FFFu);
        unsigned long long b0 = __ballot(k0 == m);
        if (b0) {
            if (lane == __ffsll((long long)b0) - 1) k0 = 0u;
        } else {
            unsigned long long b1 = __ballot(k1 == m);
            if (lane == __ffsll((long long)b1) - 1) k1 = 0u;
        }
    }
    float w[KTOP], sum = 0.f;
#pragma unroll
    for (int k = 0; k < KTOP; ++k) { w[k] = expf(s[k] - s[0]); sum += w[k]; }
    float inv = 0.5f / sum;

    int c = lane * 8;
    const float4* xp = (const float4*)(x + (size_t)q * CDIM + c);
    float4 o0 = xp[0], o1 = xp[1];
#pragma unroll
    for (int k = 0; k < KTOP; ++k) {
        float wk = w[k] * inv;
        const float4* mp = (const float4*)(mem + (size_t)id[k] * CDIM + c);
        float4 g0 = mp[0], g1 = mp[1];
        o0.x += wk * g0.x; o0.y += wk * g0.y; o0.z += wk * g0.z; o0.w += wk * g0.w;
        o1.x += wk * g1.x; o1.y += wk * g1.y; o1.z += wk * g1.z; o1.w += wk * g1.w;
    }
    float* op = out + (size_t)q * CDIM + c;
    *(float4*)op = o0;
    *(float4*)(op + 4) = o1;
}

// ---------- launcher --------------------------------------------------------
extern "C" void kernel_launch(void* const* d_in, const int* in_sizes, int n_in,
                              void* d_out, int out_size, void* d_ws, size_t ws_size,
                              hipStream_t stream) {
    const float* x    = (const float*)d_in[0];   // [4,2048,512] fp32
    const float* memM = (const float*)d_in[1];   // [32768,512] fp32
    float* out = (float*)d_out;                  // fp32 output

    // workspace layout: mn fp8 [M][512B] | qn fp8 [BS][512B] | cand u32 [BS][NC][5]
    u8* mn = (u8*)d_ws;
    u8* qn = mn + (size_t)MROWS * ROWB;
    unsigned* cand = (unsigned*)(qn + (size_t)BS * ROWB);

    nrm_cast2<<<(MROWS + BS) / 4, 256, 0, stream>>>(memM, mn, x, qn);
    simtopk<<<dim3(NC, BS / TQ), 256, 0, stream>>>(qn, mn, cand);
    epilogue<<<BS / 4, 256, 0, stream>>>(x, memM, cand, out);
}

// Round 10
// 339.905 us; speedup vs baseline: 1.7313x; 1.7313x over previous
//
#include <hip/hip_runtime.h>
#include <math.h>

using f32x4 = __attribute__((ext_vector_type(4))) float;
typedef __attribute__((ext_vector_type(4))) int i32x4;
typedef __attribute__((ext_vector_type(8))) int i32x8;
typedef unsigned char u8;

#define BS    8192
#define CDIM  512
#define MROWS 32768
#define NC    8                 // n-chunks (grid.x)
#define CHUNK (MROWS / NC)      // 4096
#define TN    32                // B-tile rows per iteration
#define TQ    128               // queries per block (32 per wave)
#define KTOP  5
#define ITERS (CHUNK / TN)      // 128
#define ROWB  512               // fp8 row bytes
#define KEY_INIT 0x3FFF8000u    // enc_key(-2.0f, 0)
#define SCL   0x7F7F7F7F        // E8M0 scale = 1.0 in all 4 bytes

// ---------- key packing: monotonic fp32 order bits [31:15] | index [14:0] ----
__device__ __forceinline__ unsigned enc_key(float s, int n) {
    unsigned u = __float_as_uint(s);
    u ^= (unsigned)((int)u >> 31) | 0x80000000u;   // monotonic map
    return (u & 0xFFFF8000u) | (unsigned)n;
}
__device__ __forceinline__ float dec_score(unsigned k) {
    unsigned u = k & 0xFFFF8000u;
    u = (u & 0x80000000u) ? (u ^ 0x80000000u) : ~u;
    return __uint_as_float(u);
}

// sorted-descending top-5 list of packed keys, branchless bubble insert
__device__ __forceinline__ void ins_nb(unsigned (&ks)[KTOP], unsigned k) {
    unsigned t = k;
#pragma unroll
    for (int j = 0; j < KTOP; ++j) {
        unsigned hi = t > ks[j] ? t : ks[j];
        unsigned lo = t > ks[j] ? ks[j] : t;
        ks[j] = hi; t = lo;
    }
}

// max across a 16-lane DPP row (VALU-only; keeps threshold syncs off LDS pipe)
__device__ __forceinline__ float dpp_fmax16(float x) {
    int t;
    t = __builtin_amdgcn_update_dpp(0, __float_as_int(x), 0xB1, 0xF, 0xF, true);  // xor 1
    x = fmaxf(x, __int_as_float(t));
    t = __builtin_amdgcn_update_dpp(0, __float_as_int(x), 0x4E, 0xF, 0xF, true);  // xor 2
    x = fmaxf(x, __int_as_float(t));
    t = __builtin_amdgcn_update_dpp(0, __float_as_int(x), 0x141, 0xF, 0xF, true); // xor 4
    x = fmaxf(x, __int_as_float(t));
    t = __builtin_amdgcn_update_dpp(0, __float_as_int(x), 0x140, 0xF, 0xF, true); // xor 8
    x = fmaxf(x, __int_as_float(t));
    return x;
}

// ---------- kernel 1: row L2-normalize fp32 -> fp8 e4m3 (both inputs) -------
__global__ void nrm_cast2(const float* __restrict__ memM, u8* __restrict__ mn,
                          const float* __restrict__ x, u8* __restrict__ qn) {
    int wave = threadIdx.x >> 6, lane = threadIdx.x & 63;
    int row = blockIdx.x * 4 + wave;
    const float* in;
    u8* out;
    if (row < MROWS) { in = memM + (size_t)row * CDIM; out = mn + (size_t)row * ROWB; }
    else             { int r = row - MROWS; in = x + (size_t)r * CDIM; out = qn + (size_t)r * ROWB; }
    const float* rp = in + lane * 8;
    float4 v0 = *(const float4*)rp;
    float4 v1 = *(const float4*)(rp + 4);
    float ss = v0.x * v0.x + v0.y * v0.y + v0.z * v0.z + v0.w * v0.w
             + v1.x * v1.x + v1.y * v1.y + v1.z * v1.z + v1.w * v1.w;
#pragma unroll
    for (int d = 1; d < 64; d <<= 1) ss += __shfl_xor(ss, d);
    float sc = 1.0f / fmaxf(sqrtf(ss), 1e-12f);
    int lo = __builtin_amdgcn_cvt_pk_fp8_f32(v0.x * sc, v0.y * sc, 0, false);
    lo     = __builtin_amdgcn_cvt_pk_fp8_f32(v0.z * sc, v0.w * sc, lo, true);
    int hi = __builtin_amdgcn_cvt_pk_fp8_f32(v1.x * sc, v1.y * sc, 0, false);
    hi     = __builtin_amdgcn_cvt_pk_fp8_f32(v1.z * sc, v1.w * sc, hi, true);
    uint2 o; o.x = (unsigned)lo; o.y = (unsigned)hi;
    *(uint2*)(out + lane * 8) = o;
}

// ---------- async staging: one call moves 2 rows (1 KB), XOR chunk swizzle --
// Row r: global 16B-chunk c stored at LDS slot c ^ (r&7). DMA dst is uniform
// base + lane*16; lane i covers row r0+2j+(i>>5), chunk (i&31)^(row&7) --
// the XOR stays inside the row's 512B, global access is one 1KB segment.
__device__ __forceinline__ void stage_tile(const u8* __restrict__ mn, int nb,
                                           u8* buf, int wave, int lane) {
    const int r0 = wave * 8;
    const int li = lane & 31, half = lane >> 5;
#pragma unroll
    for (int j = 0; j < 4; ++j) {
        const int row = r0 + 2 * j + half;
        const u8* src = mn + (size_t)(nb + row) * ROWB + ((li ^ (row & 7)) * 16);
        __builtin_amdgcn_global_load_lds(
            (const __attribute__((address_space(1))) void*)src,
            (__attribute__((address_space(3))) void*)(buf + (r0 + 2 * j) * ROWB),
            16, 0, 0);
    }
}

// ---------- kernel 2: fused MX-fp8 MFMA sim + per-chunk top-5 ---------------
// grid = (NC, BS/TQ) = (8,64), block 256 (4 waves), 2 blocks/CU.
// Round-6 base (239us). ONE change: stage_tile(it+1) moved from right-after-
// the-barrier to AFTER the MFMA t-loop. Theory: SQ_LDS_BANK_CONFLICT=1.68e7
// (~16 extra cyc per ds_read_b128, ~11% of wall) is read-vs-DMA-write port
// collision -- the old schedule put the DMA writes exactly in the barrier-
// phase-aligned window where all 8 waves issue their 16 b128 reads. Staging
// after the reads lands the DMA during the filter/MFMA tail instead; the
// filter (~600 issue cyc) + barrier skew covers the L2-resident DMA latency.
__global__ __launch_bounds__(256, 2) void simtopk(
        const u8* __restrict__ qn, const u8* __restrict__ mn,
        unsigned* __restrict__ cand) {
    __shared__ __align__(16) u8 Bt[2][TN * ROWB];   // 2 x 16 KiB

    const int tid  = threadIdx.x;
    const int wave = tid >> 6, lane = tid & 63;
    const int quad = lane >> 4, c16 = lane & 15;
    const int nc = blockIdx.x;
    const int qt = blockIdx.y;
    const int qw = qt * TQ + wave * 32;
    const int nb0 = nc * CHUNK;

    // persistent A fragments: 2 q-subtiles x 4 k128-chunks x 32B = 64 VGPRs
    i32x8 a[2][4];
#pragma unroll
    for (int s = 0; s < 2; ++s) {
        const u8* p = qn + (size_t)(qw + s * 16 + c16) * ROWB + quad * 32;
#pragma unroll
        for (int t = 0; t < 4; ++t) {
            i32x4 lo = *(const i32x4*)(p + t * 128);
            i32x4 hi = *(const i32x4*)(p + t * 128 + 16);
            a[s][t] = __builtin_shufflevector(lo, hi, 0, 1, 2, 3, 4, 5, 6, 7);
        }
    }

    unsigned keys[8][KTOP];
    float thr[8];
#pragma unroll
    for (int l = 0; l < 8; ++l) {
        thr[l] = -2.0f;
#pragma unroll
        for (int j = 0; j < KTOP; ++j) keys[l][j] = KEY_INIT;
    }

    const int sw  = c16 & 7;                             // read-side slot XOR
    const int pb0 = c16 * ROWB + (((2 * quad) ^ sw) * 16);

    // carried (previous-tile) accumulators + their row indices
    f32x4 p00 = {-2.f, -2.f, -2.f, -2.f};
    f32x4 p01 = p00, p10 = p00, p11 = p00;
    int np0 = nb0, np1 = nb0;

    stage_tile(mn, nb0, &Bt[0][0], wave, lane);   // prefetch tile 0

    for (int it = 0; it < ITERS; ++it) {
        __syncthreads();   // drains async loads; syncs waves

        // ---- ds_read + MFMA on tile it (DMA-quiet window) ----
        const u8* bb = &Bt[it & 1][0];
        f32x4 acc00 = {0.f, 0.f, 0.f, 0.f}, acc01 = {0.f, 0.f, 0.f, 0.f};
        f32x4 acc10 = {0.f, 0.f, 0.f, 0.f}, acc11 = {0.f, 0.f, 0.f, 0.f};
#pragma unroll
        for (int t = 0; t < 4; ++t) {
            i32x4 l0 = *(const i32x4*)(bb + pb0 + t * 128);            // row c16
            i32x4 h0 = *(const i32x4*)(bb + (pb0 ^ 16) + t * 128);
            i32x8 b0 = __builtin_shufflevector(l0, h0, 0, 1, 2, 3, 4, 5, 6, 7);
            acc00 = __builtin_amdgcn_mfma_scale_f32_16x16x128_f8f6f4(
                        a[0][t], b0, acc00, 0, 0, 0, SCL, 0, SCL);
            acc10 = __builtin_amdgcn_mfma_scale_f32_16x16x128_f8f6f4(
                        a[1][t], b0, acc10, 0, 0, 0, SCL, 0, SCL);
            i32x4 l1 = *(const i32x4*)(bb + pb0 + 16 * ROWB + t * 128); // row 16+c16
            i32x4 h1 = *(const i32x4*)(bb + (pb0 ^ 16) + 16 * ROWB + t * 128);
            i32x8 b1 = __builtin_shufflevector(l1, h1, 0, 1, 2, 3, 4, 5, 6, 7);
            acc01 = __builtin_amdgcn_mfma_scale_f32_16x16x128_f8f6f4(
                        a[0][t], b1, acc01, 0, 0, 0, SCL, 0, SCL);
            acc11 = __builtin_amdgcn_mfma_scale_f32_16x16x128_f8f6f4(
                        a[1][t], b1, acc11, 0, 0, 0, SCL, 0, SCL);
        }

        // ---- NOW issue next tile's DMA: writes land while waves run the
        //      filter / other waves' MFMAs, not during the read burst ----
        if (it + 1 < ITERS)
            stage_tile(mn, nb0 + (it + 1) * TN, &Bt[(it + 1) & 1][0], wave, lane);

        // filter PREVIOUS tile's accs (independent of this tile's MFMAs)
#pragma unroll
        for (int j = 0; j < 4; ++j) {
            if (p00[j] > thr[j])     ins_nb(keys[j],     enc_key(p00[j], np0));
            if (p01[j] > thr[j])     ins_nb(keys[j],     enc_key(p01[j], np1));
            if (p10[j] > thr[4 + j]) ins_nb(keys[4 + j], enc_key(p10[j], np0));
            if (p11[j] > thr[4 + j]) ins_nb(keys[4 + j], enc_key(p11[j], np1));
        }
        if ((it & 3) == 3) {
#pragma unroll
            for (int l = 0; l < 8; ++l)
                thr[l] = dpp_fmax16(fmaxf(thr[l], dec_score(keys[l][KTOP - 1])));
        }

        // rotate: current accs become next iteration's filter input
        p00 = acc00; p01 = acc01; p10 = acc10; p11 = acc11;
        np0 = nb0 + it * TN + c16;
        np1 = np0 + 16;
    }

    // drain the final tile's accumulators
#pragma unroll
    for (int j = 0; j < 4; ++j) {
        if (p00[j] > thr[j])     ins_nb(keys[j],     enc_key(p00[j], np0));
        if (p01[j] > thr[j])     ins_nb(keys[j],     enc_key(p01[j], np1));
        if (p10[j] > thr[4 + j]) ins_nb(keys[4 + j], enc_key(p10[j], np0));
        if (p11[j] > thr[4 + j]) ins_nb(keys[4 + j], enc_key(p11[j], np1));
    }

    // merge the 16 column-lanes of each quad (disjoint n subsets -> union top5)
#pragma unroll
    for (int d = 1; d <= 8; d <<= 1) {
#pragma unroll
        for (int l = 0; l < 8; ++l) {
            unsigned rk[KTOP];
#pragma unroll
            for (int j = 0; j < KTOP; ++j) rk[j] = (unsigned)__shfl_xor((int)keys[l][j], d);
#pragma unroll
            for (int j = 0; j < KTOP; ++j) ins_nb(keys[l], rk[j]);
        }
    }

    // writer lane c16==l emits list l for query qw + (l>>2)*16 + quad*4 + (l&3)
#pragma unroll
    for (int l = 0; l < 8; ++l) {
        if (c16 == l) {
            const int q = qw + (l >> 2) * 16 + quad * 4 + (l & 3);
            unsigned* cp = cand + ((size_t)q * NC + nc) * KTOP;
#pragma unroll
            for (int j = 0; j < KTOP; ++j) cp[j] = keys[l][j];
        }
    }
}

// ---------- kernel 3: global top-5 merge + softmax + gather + residual ------
__global__ void epilogue(const float* __restrict__ x, const float* __restrict__ mem,
                         const unsigned* __restrict__ cand, float* __restrict__ out) {
    int wave = threadIdx.x >> 6, lane = threadIdx.x & 63;
    int q = blockIdx.x * 4 + wave;

    unsigned key = (lane < NC * KTOP) ? cand[(size_t)q * (NC * KTOP) + lane] : 0u;
    float s[KTOP]; int id[KTOP];
#pragma unroll
    for (int k = 0; k < KTOP; ++k) {
        unsigned m = key;
#pragma unroll
        for (int d = 32; d; d >>= 1) {
            unsigned o = (unsigned)__shfl_xor((int)m, d);
            m = o > m ? o : m;
        }
        s[k] = dec_score(m);
        id[k] = (int)(m & 0x7FFFu);
        unsigned long long b = __ballot(key == m);
        int first = __ffsll((long long)b) - 1;
        if (lane == first) key = 0u;
    }
    float w[KTOP], sum = 0.f;
#pragma unroll
    for (int k = 0; k < KTOP; ++k) { w[k] = expf(s[k] - s[0]); sum += w[k]; }
    float inv = 0.5f / sum;

    int c = lane * 8;
    const float4* xp = (const float4*)(x + (size_t)q * CDIM + c);
    float4 o0 = xp[0], o1 = xp[1];
#pragma unroll
    for (int k = 0; k < KTOP; ++k) {
        float wk = w[k] * inv;
        const float4* mp = (const float4*)(mem + (size_t)id[k] * CDIM + c);
        float4 g0 = mp[0], g1 = mp[1];
        o0.x += wk * g0.x; o0.y += wk * g0.y; o0.z += wk * g0.z; o0.w += wk * g0.w;
        o1.x += wk * g1.x; o1.y += wk * g1.y; o1.z += wk * g1.z; o1.w += wk * g1.w;
    }
    float* op = out + (size_t)q * CDIM + c;
    *(float4*)op = o0;
    *(float4*)(op + 4) = o1;
}

// ---------- launcher --------------------------------------------------------
extern "C" void kernel_launch(void* const* d_in, const int* in_sizes, int n_in,
                              void* d_out, int out_size, void* d_ws, size_t ws_size,
                              hipStream_t stream) {
    const float* x    = (const float*)d_in[0];   // [4,2048,512] fp32
    const float* memM = (const float*)d_in[1];   // [32768,512] fp32
    float* out = (float*)d_out;                  // fp32 output

    // workspace layout: mn fp8 [M][512B] | qn fp8 [BS][512B] | cand u32 [BS][NC][5]
    u8* mn = (u8*)d_ws;
    u8* qn = mn + (size_t)MROWS * ROWB;
    unsigned* cand = (unsigned*)(qn + (size_t)BS * ROWB);

    nrm_cast2<<<(MROWS + BS) / 4, 256, 0, stream>>>(memM, mn, x, qn);
    simtopk<<<dim3(NC, BS / TQ), 256, 0, stream>>>(qn, mn, cand);
    epilogue<<<BS / 4, 256, 0, stream>>>(x, memM, cand, out);
}

// Round 12
// 297.974 us; speedup vs baseline: 1.9750x; 1.1407x over previous
//
#include <hip/hip_runtime.h>
#include <math.h>

using f32x4 = __attribute__((ext_vector_type(4))) float;
typedef __attribute__((ext_vector_type(4))) int i32x4;
typedef __attribute__((ext_vector_type(8))) int i32x8;
typedef unsigned char u8;

#define BS    8192
#define CDIM  512
#define MROWS 32768
#define NC    8                 // n-chunks (grid.x)
#define CHUNK (MROWS / NC)      // 4096
#define TN    32                // B-tile rows per iteration
#define TQ    128               // queries per block (32 per wave)
#define KTOP  5
#define ITERS (CHUNK / TN)      // 128
#define ROWB  512               // fp8 row bytes
#define KEY_INIT 0x3FFF8000u    // enc_key(-2.0f, 0)
#define SCL   0x7F7F7F7F        // E8M0 scale = 1.0 in all 4 bytes

// ---------- key packing: monotonic fp32 order bits [31:15] | index [14:0] ----
__device__ __forceinline__ unsigned enc_key(float s, int n) {
    unsigned u = __float_as_uint(s);
    u ^= (unsigned)((int)u >> 31) | 0x80000000u;   // monotonic map
    return (u & 0xFFFF8000u) | (unsigned)n;
}
__device__ __forceinline__ float dec_score(unsigned k) {
    unsigned u = k & 0xFFFF8000u;
    u = (u & 0x80000000u) ? (u ^ 0x80000000u) : ~u;
    return __uint_as_float(u);
}

// sorted-descending top-5 list of packed keys, branchless bubble insert
__device__ __forceinline__ void ins_nb(unsigned (&ks)[KTOP], unsigned k) {
    unsigned t = k;
#pragma unroll
    for (int j = 0; j < KTOP; ++j) {
        unsigned hi = t > ks[j] ? t : ks[j];
        unsigned lo = t > ks[j] ? ks[j] : t;
        ks[j] = hi; t = lo;
    }
}

// ---------- kernel 1: row L2-normalize fp32 -> fp8 e4m3 (both inputs) -------
__global__ void nrm_cast2(const float* __restrict__ memM, u8* __restrict__ mn,
                          const float* __restrict__ x, u8* __restrict__ qn) {
    int wave = threadIdx.x >> 6, lane = threadIdx.x & 63;
    int row = blockIdx.x * 4 + wave;
    const float* in;
    u8* out;
    if (row < MROWS) { in = memM + (size_t)row * CDIM; out = mn + (size_t)row * ROWB; }
    else             { int r = row - MROWS; in = x + (size_t)r * CDIM; out = qn + (size_t)r * ROWB; }
    const float* rp = in + lane * 8;
    float4 v0 = *(const float4*)rp;
    float4 v1 = *(const float4*)(rp + 4);
    float ss = v0.x * v0.x + v0.y * v0.y + v0.z * v0.z + v0.w * v0.w
             + v1.x * v1.x + v1.y * v1.y + v1.z * v1.z + v1.w * v1.w;
#pragma unroll
    for (int d = 1; d < 64; d <<= 1) ss += __shfl_xor(ss, d);
    float sc = 1.0f / fmaxf(sqrtf(ss), 1e-12f);
    int lo = __builtin_amdgcn_cvt_pk_fp8_f32(v0.x * sc, v0.y * sc, 0, false);
    lo     = __builtin_amdgcn_cvt_pk_fp8_f32(v0.z * sc, v0.w * sc, lo, true);
    int hi = __builtin_amdgcn_cvt_pk_fp8_f32(v1.x * sc, v1.y * sc, 0, false);
    hi     = __builtin_amdgcn_cvt_pk_fp8_f32(v1.z * sc, v1.w * sc, hi, true);
    uint2 o; o.x = (unsigned)lo; o.y = (unsigned)hi;
    *(uint2*)(out + lane * 8) = o;
}

// ---------- async staging: one call moves 2 rows (1 KB), XOR chunk swizzle --
// Row r: global 16B-chunk c stored at LDS slot c ^ (r&7). DMA dst is uniform
// base + lane*16; lane i covers row r0+2j+(i>>5), chunk (i&31)^(row&7) --
// the XOR stays inside the row's 512B, global access is one 1KB segment.
__device__ __forceinline__ void stage_tile(const u8* __restrict__ mn, int nb,
                                           u8* buf, int wave, int lane) {
    const int r0 = wave * 8;
    const int li = lane & 31, half = lane >> 5;
#pragma unroll
    for (int j = 0; j < 4; ++j) {
        const int row = r0 + 2 * j + half;
        const u8* src = mn + (size_t)(nb + row) * ROWB + ((li ^ (row & 7)) * 16);
        __builtin_amdgcn_global_load_lds(
            (const __attribute__((address_space(1))) void*)src,
            (__attribute__((address_space(3))) void*)(buf + (r0 + 2 * j) * ROWB),
            16, 0, 0);
    }
}

// ---------- kernel 2: fused MX-fp8 MFMA sim + per-chunk top-5 ---------------
// grid = (NC, BS/TQ) = (8,64), block 256 (4 waves), 2 blocks/CU.
// Round-10 base (239.7us) with two changes:
// (1) threshold machinery DELETED: the `if (p>thr)` guards were if-converted,
//     so the 5-stage insert executed predicated regardless -- thr only added
//     16 cmps/iter + the every-4-iter dpp block (~45 instr/iter) + 8 VGPRs.
//     Unconditional ins_nb of every value is equally exact and cheaper.
// (2) T5 s_setprio(1) around the MFMA cluster: the 2 co-resident blocks are
//     barrier-independent (phase diversity on the CU), so priority keeps the
//     matrix pipe fed while the other block's waves issue filter VALU.
__global__ __launch_bounds__(256, 2) void simtopk(
        const u8* __restrict__ qn, const u8* __restrict__ mn,
        unsigned* __restrict__ cand) {
    __shared__ __align__(16) u8 Bt[2][TN * ROWB];   // 2 x 16 KiB

    const int tid  = threadIdx.x;
    const int wave = tid >> 6, lane = tid & 63;
    const int quad = lane >> 4, c16 = lane & 15;
    const int nc = blockIdx.x;
    const int qt = blockIdx.y;
    const int qw = qt * TQ + wave * 32;
    const int nb0 = nc * CHUNK;

    // persistent A fragments: 2 q-subtiles x 4 k128-chunks x 32B = 64 VGPRs
    i32x8 a[2][4];
#pragma unroll
    for (int s = 0; s < 2; ++s) {
        const u8* p = qn + (size_t)(qw + s * 16 + c16) * ROWB + quad * 32;
#pragma unroll
        for (int t = 0; t < 4; ++t) {
            i32x4 lo = *(const i32x4*)(p + t * 128);
            i32x4 hi = *(const i32x4*)(p + t * 128 + 16);
            a[s][t] = __builtin_shufflevector(lo, hi, 0, 1, 2, 3, 4, 5, 6, 7);
        }
    }

    unsigned keys[8][KTOP];
#pragma unroll
    for (int l = 0; l < 8; ++l)
#pragma unroll
        for (int j = 0; j < KTOP; ++j) keys[l][j] = KEY_INIT;

    const int sw  = c16 & 7;                             // read-side slot XOR
    const int pb0 = c16 * ROWB + (((2 * quad) ^ sw) * 16);

    // carried (previous-tile) accumulators + their row indices
    f32x4 p00 = {-2.f, -2.f, -2.f, -2.f};
    f32x4 p01 = p00, p10 = p00, p11 = p00;
    int np0 = nb0, np1 = nb0;

    stage_tile(mn, nb0, &Bt[0][0], wave, lane);   // prefetch tile 0

    for (int it = 0; it < ITERS; ++it) {
        __syncthreads();   // drains async loads; syncs waves

        // ---- ds_read + MFMA on tile it (priority-boosted) ----
        const u8* bb = &Bt[it & 1][0];
        f32x4 acc00 = {0.f, 0.f, 0.f, 0.f}, acc01 = {0.f, 0.f, 0.f, 0.f};
        f32x4 acc10 = {0.f, 0.f, 0.f, 0.f}, acc11 = {0.f, 0.f, 0.f, 0.f};
        __builtin_amdgcn_s_setprio(1);
#pragma unroll
        for (int t = 0; t < 4; ++t) {
            i32x4 l0 = *(const i32x4*)(bb + pb0 + t * 128);            // row c16
            i32x4 h0 = *(const i32x4*)(bb + (pb0 ^ 16) + t * 128);
            i32x8 b0 = __builtin_shufflevector(l0, h0, 0, 1, 2, 3, 4, 5, 6, 7);
            acc00 = __builtin_amdgcn_mfma_scale_f32_16x16x128_f8f6f4(
                        a[0][t], b0, acc00, 0, 0, 0, SCL, 0, SCL);
            acc10 = __builtin_amdgcn_mfma_scale_f32_16x16x128_f8f6f4(
                        a[1][t], b0, acc10, 0, 0, 0, SCL, 0, SCL);
            i32x4 l1 = *(const i32x4*)(bb + pb0 + 16 * ROWB + t * 128); // row 16+c16
            i32x4 h1 = *(const i32x4*)(bb + (pb0 ^ 16) + 16 * ROWB + t * 128);
            i32x8 b1 = __builtin_shufflevector(l1, h1, 0, 1, 2, 3, 4, 5, 6, 7);
            acc01 = __builtin_amdgcn_mfma_scale_f32_16x16x128_f8f6f4(
                        a[0][t], b1, acc01, 0, 0, 0, SCL, 0, SCL);
            acc11 = __builtin_amdgcn_mfma_scale_f32_16x16x128_f8f6f4(
                        a[1][t], b1, acc11, 0, 0, 0, SCL, 0, SCL);
        }
        __builtin_amdgcn_s_setprio(0);

        // issue next tile's DMA (position measured neutral vs pre-MFMA)
        if (it + 1 < ITERS)
            stage_tile(mn, nb0 + (it + 1) * TN, &Bt[(it + 1) & 1][0], wave, lane);

        // unconditional filter of PREVIOUS tile's accs (no thr: the insert
        // was predicated-executed anyway; top-5 of all inserted = exact)
#pragma unroll
        for (int j = 0; j < 4; ++j) {
            ins_nb(keys[j],     enc_key(p00[j], np0));
            ins_nb(keys[j],     enc_key(p01[j], np1));
            ins_nb(keys[4 + j], enc_key(p10[j], np0));
            ins_nb(keys[4 + j], enc_key(p11[j], np1));
        }

        // rotate: current accs become next iteration's filter input
        p00 = acc00; p01 = acc01; p10 = acc10; p11 = acc11;
        np0 = nb0 + it * TN + c16;
        np1 = np0 + 16;
    }

    // drain the final tile's accumulators
#pragma unroll
    for (int j = 0; j < 4; ++j) {
        ins_nb(keys[j],     enc_key(p00[j], np0));
        ins_nb(keys[j],     enc_key(p01[j], np1));
        ins_nb(keys[4 + j], enc_key(p10[j], np0));
        ins_nb(keys[4 + j], enc_key(p11[j], np1));
    }

    // merge the 16 column-lanes of each quad (disjoint n subsets -> union top5)
#pragma unroll
    for (int d = 1; d <= 8; d <<= 1) {
#pragma unroll
        for (int l = 0; l < 8; ++l) {
            unsigned rk[KTOP];
#pragma unroll
            for (int j = 0; j < KTOP; ++j) rk[j] = (unsigned)__shfl_xor((int)keys[l][j], d);
#pragma unroll
            for (int j = 0; j < KTOP; ++j) ins_nb(keys[l], rk[j]);
        }
    }

    // writer lane c16==l emits list l for query qw + (l>>2)*16 + quad*4 + (l&3)
#pragma unroll
    for (int l = 0; l < 8; ++l) {
        if (c16 == l) {
            const int q = qw + (l >> 2) * 16 + quad * 4 + (l & 3);
            unsigned* cp = cand + ((size_t)q * NC + nc) * KTOP;
#pragma unroll
            for (int j = 0; j < KTOP; ++j) cp[j] = keys[l][j];
        }
    }
}

// ---------- kernel 3: global top-5 merge + softmax + gather + residual ------
__global__ void epilogue(const float* __restrict__ x, const float* __restrict__ mem,
                         const unsigned* __restrict__ cand, float* __restrict__ out) {
    int wave = threadIdx.x >> 6, lane = threadIdx.x & 63;
    int q = blockIdx.x * 4 + wave;

    unsigned key = (lane < NC * KTOP) ? cand[(size_t)q * (NC * KTOP) + lane] : 0u;
    float s[KTOP]; int id[KTOP];
#pragma unroll
    for (int k = 0; k < KTOP; ++k) {
        unsigned m = key;
#pragma unroll
        for (int d = 32; d; d >>= 1) {
            unsigned o = (unsigned)__shfl_xor((int)m, d);
            m = o > m ? o : m;
        }
        s[k] = dec_score(m);
        id[k] = (int)(m & 0x7FFFu);
        unsigned long long b = __ballot(key == m);
        int first = __ffsll((long long)b) - 1;
        if (lane == first) key = 0u;
    }
    float w[KTOP], sum = 0.f;
#pragma unroll
    for (int k = 0; k < KTOP; ++k) { w[k] = expf(s[k] - s[0]); sum += w[k]; }
    float inv = 0.5f / sum;

    int c = lane * 8;
    const float4* xp = (const float4*)(x + (size_t)q * CDIM + c);
    float4 o0 = xp[0], o1 = xp[1];
#pragma unroll
    for (int k = 0; k < KTOP; ++k) {
        float wk = w[k] * inv;
        const float4* mp = (const float4*)(mem + (size_t)id[k] * CDIM + c);
        float4 g0 = mp[0], g1 = mp[1];
        o0.x += wk * g0.x; o0.y += wk * g0.y; o0.z += wk * g0.z; o0.w += wk * g0.w;
        o1.x += wk * g1.x; o1.y += wk * g1.y; o1.z += wk * g1.z; o1.w += wk * g1.w;
    }
    float* op = out + (size_t)q * CDIM + c;
    *(float4*)op = o0;
    *(float4*)(op + 4) = o1;
}

// ---------- launcher --------------------------------------------------------
extern "C" void kernel_launch(void* const* d_in, const int* in_sizes, int n_in,
                              void* d_out, int out_size, void* d_ws, size_t ws_size,
                              hipStream_t stream) {
    const float* x    = (const float*)d_in[0];   // [4,2048,512] fp32
    const float* memM = (const float*)d_in[1];   // [32768,512] fp32
    float* out = (float*)d_out;                  // fp32 output

    // workspace layout: mn fp8 [M][512B] | qn fp8 [BS][512B] | cand u32 [BS][NC][5]
    u8* mn = (u8*)d_ws;
    u8* qn = mn + (size_t)MROWS * ROWB;
    unsigned* cand = (unsigned*)(qn + (size_t)BS * ROWB);

    nrm_cast2<<<(MROWS + BS) / 4, 256, 0, stream>>>(memM, mn, x, qn);
    simtopk<<<dim3(NC, BS / TQ), 256, 0, stream>>>(qn, mn, cand);
    epilogue<<<BS / 4, 256, 0, stream>>>(x, memM, cand, out);
}